// Round 11
// baseline (362.889 us; speedup 1.0000x reference)
//
#include <hip/hip_runtime.h>
#include <math.h>

#define H 4
#define HD 64
#define NN 1024
#define BB 8
#define FIN 256
#define FOUT 256

typedef _Float16 f16x8 __attribute__((ext_vector_type(8)));
typedef _Float16 f16x4 __attribute__((ext_vector_type(4)));
typedef _Float16 f16x2 __attribute__((ext_vector_type(2)));
typedef float f32x4 __attribute__((ext_vector_type(4)));

__device__ __forceinline__ unsigned fkey(float f) {
  unsigned u = __float_as_uint(f);
  return (u & 0x80000000u) ? ~u : (u | 0x80000000u);
}
__device__ __forceinline__ float fdecode(unsigned k) {
  unsigned u = (k & 0x80000000u) ? (k & 0x7fffffffu) : ~k;
  return __uint_as_float(u);
}

// ---------------------------------------------------------------------------
// Kernel 0: prep. Blocks 0..1023: pack adj -> 1 bit/edge (streaming).
// Blocks 1024..1039: WT[f][k] = (fp16) W[k][f]; block 1024 also zeroes S2maxU.
// ---------------------------------------------------------------------------
__global__ __launch_bounds__(256) void prep(const int* __restrict__ adj,
                                            unsigned* __restrict__ adjP,
                                            const float* __restrict__ W,
                                            _Float16* __restrict__ WT,
                                            unsigned* __restrict__ S2maxU) {
  __shared__ float tile[64][68];
  const int tid = threadIdx.x;
  if (blockIdx.x < 1024) {
    size_t widx = (size_t)blockIdx.x * 256 + tid;  // [0, 8*1024*32)
    const int4* p = (const int4*)adj + widx * 8;
    int4 v[8];
#pragma unroll
    for (int i = 0; i < 8; ++i) v[i] = p[i];
    unsigned bits = 0;
#pragma unroll
    for (int i = 0; i < 8; ++i) {
      bits |= (v[i].x != 0 ? 1u : 0u) << (4 * i);
      bits |= (v[i].y != 0 ? 2u : 0u) << (4 * i);
      bits |= (v[i].z != 0 ? 4u : 0u) << (4 * i);
      bits |= (v[i].w != 0 ? 8u : 0u) << (4 * i);
    }
    adjP[widx] = bits;
  } else {
    if (blockIdx.x == 1024 && tid < 32) S2maxU[tid] = 0u;
    const int bx = blockIdx.x - 1024;
    const int k0 = (bx & 3) * 64, f0 = (bx >> 2) * 64;
    const int r = tid >> 4, c4 = (tid & 15) * 4;
#pragma unroll
    for (int p = 0; p < 4; ++p) {
      float4 v = *(const float4*)&W[(size_t)(k0 + p * 16 + r) * FOUT + f0 + c4];
      *(float4*)&tile[p * 16 + r][c4] = v;
    }
    __syncthreads();
    const int f = tid >> 2, kg = (tid & 3) * 16;
#pragma unroll
    for (int i = 0; i < 4; ++i) {
      f16x4 o;
#pragma unroll
      for (int j = 0; j < 4; ++j) o[j] = (_Float16)tile[kg + i * 4 + j][f];
      *(f16x4*)&WT[(size_t)(f0 + f) * FIN + k0 + kg + i * 4] = o;
    }
  }
}

// ---------------------------------------------------------------------------
// Kernel 1: h = x @ W via fp16 MFMA (validated r7 structure). Epilogue
// stores s1, u=exp(s2), v=exp(0.2*s2) (fp32, unshifted — safe in fp32) and
// per-(b,h) atomicMax of s2.
// ---------------------------------------------------------------------------
__global__ __launch_bounds__(256) void gemm_xw(const float* __restrict__ x,
                                               const _Float16* __restrict__ WT,
                                               const float* __restrict__ a,
                                               _Float16* __restrict__ hT,
                                               float* __restrict__ s1_ws,
                                               float* __restrict__ u_ws,
                                               float* __restrict__ v_ws,
                                               unsigned* __restrict__ S2maxU) {
  __shared__ _Float16 wl[64][264];
  const int tid = threadIdx.x;
  const int lane = tid & 63, w = tid >> 6;
  const int c = lane & 15, q = lane >> 4;
  const int bn0 = blockIdx.x * 64;
  const int head = blockIdx.y;
  const int b = bn0 >> 10, nb = bn0 & 1023;
  const int bh = b * H + head;

  {
    const int row = tid >> 2, kseg = (tid & 3) * 64;
    const _Float16* wp = WT + (size_t)(head * 64 + row) * FIN + kseg;
#pragma unroll
    for (int i = 0; i < 8; ++i) {
      f16x8 t = *(const f16x8*)(wp + i * 8);
      *(f16x8*)&wl[row][kseg + i * 8] = t;
    }
  }
  __syncthreads();

  f32x4 acc[4];
#pragma unroll
  for (int t = 0; t < 4; ++t) acc[t] = (f32x4){0.f, 0.f, 0.f, 0.f};
  const float* xp = x + (size_t)(bn0 + w * 16 + c) * FIN + q * 8;
#pragma unroll
  for (int ks = 0; ks < 8; ++ks) {
    float4 xa = *(const float4*)(xp + ks * 32);
    float4 xb = *(const float4*)(xp + ks * 32 + 4);
    f16x8 af;
    af[0] = (_Float16)xa.x; af[1] = (_Float16)xa.y;
    af[2] = (_Float16)xa.z; af[3] = (_Float16)xa.w;
    af[4] = (_Float16)xb.x; af[5] = (_Float16)xb.y;
    af[6] = (_Float16)xb.z; af[7] = (_Float16)xb.w;
#pragma unroll
    for (int t = 0; t < 4; ++t) {
      f16x8 bf = *(const f16x8*)&wl[t * 16 + c][ks * 32 + q * 8];
      acc[t] = __builtin_amdgcn_mfma_f32_16x16x32_f16(af, bf, acc[t], 0, 0, 0);
    }
  }

  float a1v[4], a2v[4];
#pragma unroll
  for (int t = 0; t < 4; ++t) {
    a1v[t] = a[head * 2 * HD + t * 16 + c];
    a2v[t] = a[head * 2 * HD + HD + t * 16 + c];
  }
  float s1p[4] = {0.f, 0.f, 0.f, 0.f};
  float s2p[4] = {0.f, 0.f, 0.f, 0.f};
#pragma unroll
  for (int t = 0; t < 4; ++t) {
    f16x4 hv;
#pragma unroll
    for (int rr = 0; rr < 4; ++rr) {
      hv[rr] = (_Float16)acc[t][rr];
      s1p[rr] += acc[t][rr] * a1v[t];
      s2p[rr] += acc[t][rr] * a2v[t];
    }
    *(f16x4*)&hT[((size_t)(bh * 64 + t * 16 + c)) * NN + nb + w * 16 + q * 4] = hv;
  }
  float ms2 = -INFINITY;
#pragma unroll
  for (int rr = 0; rr < 4; ++rr) {
    float s1 = s1p[rr], s2 = s2p[rr];
#pragma unroll
    for (int off = 8; off; off >>= 1) {
      s1 += __shfl_xor(s1, off);
      s2 += __shfl_xor(s2, off);
    }
    ms2 = fmaxf(ms2, s2);
    if (c == 0) {
      int n = nb + w * 16 + q * 4 + rr;
      size_t idx = (size_t)bh * NN + n;
      s1_ws[idx] = s1;
      u_ws[idx] = __expf(s2);
      v_ws[idx] = __expf(0.2f * s2);
    }
  }
  ms2 = fmaxf(ms2, __shfl_xor(ms2, 16));
  ms2 = fmaxf(ms2, __shfl_xor(ms2, 32));
  if (lane == 0) atomicMax(&S2maxU[bh], fkey(ms2));
}

// ---------------------------------------------------------------------------
// Kernel 2: attention. Block = 32 rows x (b,h): 1024 blocks (4/CU natural).
// NO LDS in the hot loop: u/v fp32 from global (L2), hT B-frags from global,
// all depth-2 prefetched. p = max(Ar*u, Br*v); M = lrelu(s1 + S2max_bh);
// L via ones-column MFMA; rcp epilogue. Masks (LDS) only on sparse path.
// ---------------------------------------------------------------------------
__global__ __launch_bounds__(256) void attn(const _Float16* __restrict__ hT,
                                            const float* __restrict__ s1_ws,
                                            const float* __restrict__ u_ws,
                                            const float* __restrict__ v_ws,
                                            const unsigned* __restrict__ S2maxU,
                                            const unsigned* __restrict__ adjP,
                                            float* __restrict__ out) {
  __shared__ unsigned adjW[32][36];  // 4.6 KB, padded
  __shared__ int denseFlag;
  const int tid = threadIdx.x, lane = tid & 63, wv = tid >> 6;
  const int c = lane & 15, q = lane >> 4;
  const int ntile = blockIdx.x, bh = blockIdx.y;
  const int b = bh >> 2, head = bh & 3;
  const int n0 = ntile * 32;

  if (tid == 0) denseFlag = 1;
  __syncthreads();
  {
    const int row = tid >> 3, wo = (tid & 7) * 4;  // 32 rows x 32 words
    uint4 m0 = *(const uint4*)(adjP + ((size_t)(b * NN + n0 + row)) * 32 + wo);
    *(uint4*)&adjW[row][wo] = m0;
    if ((m0.x & m0.y & m0.z & m0.w) != 0xffffffffu) atomicAnd(&denseFlag, 0);
  }
  __syncthreads();
  const int dense = denseFlag;

  const float S2 = fdecode(S2maxU[bh]);
  float Arf[2], Brf[2];
#pragma unroll
  for (int g = 0; g < 2; ++g) {
    float s1 = s1_ws[(size_t)bh * NN + n0 + g * 16 + c];
    float t = s1 + S2;
    float M = fmaxf(t, 0.2f * t);
    Arf[g] = __expf(s1 - M);
    Brf[g] = __expf(0.2f * s1 - M);
  }

  f32x4 acc[2], accL[2];
#pragma unroll
  for (int g = 0; g < 2; ++g) {
    acc[g] = (f32x4){0.f, 0.f, 0.f, 0.f};
    accL[g] = (f32x4){0.f, 0.f, 0.f, 0.f};
  }
  f16x8 bones;
  {
    _Float16 o = (c == 0) ? (_Float16)1.0f : (_Float16)0.0f;
#pragma unroll
    for (int j = 0; j < 8; ++j) bones[j] = o;
  }

  const _Float16* bp = hT + ((size_t)bh * 64 + wv * 16 + c) * NN + q * 8;
  const float* up = u_ws + (size_t)bh * NN + q * 8;
  const float* vp = v_ws + (size_t)bh * NN + q * 8;

  f16x8 nbf[2];
  float4 nu[2][2], nv[2][2];
#pragma unroll
  for (int s = 0; s < 2; ++s) {
    nbf[s] = *(const f16x8*)(bp + s * 32);
    nu[s][0] = *(const float4*)(up + s * 32);
    nu[s][1] = *(const float4*)(up + s * 32 + 4);
    nv[s][0] = *(const float4*)(vp + s * 32);
    nv[s][1] = *(const float4*)(vp + s * 32 + 4);
  }

  for (int kc = 0; kc < 32; ++kc) {
    const int sl = kc & 1;
    f16x8 bf = nbf[sl];
    float4 ua = nu[sl][0], ub = nu[sl][1];
    float4 va = nv[sl][0], vb = nv[sl][1];
    if (kc < 30) {
      nbf[sl] = *(const f16x8*)(bp + (kc + 2) * 32);
      nu[sl][0] = *(const float4*)(up + (kc + 2) * 32);
      nu[sl][1] = *(const float4*)(up + (kc + 2) * 32 + 4);
      nv[sl][0] = *(const float4*)(vp + (kc + 2) * 32);
      nv[sl][1] = *(const float4*)(vp + (kc + 2) * 32 + 4);
    }
    unsigned mword[2];
    if (!dense) {
#pragma unroll
      for (int g = 0; g < 2; ++g) mword[g] = adjW[g * 16 + c][kc];
    }
#pragma unroll
    for (int g = 0; g < 2; ++g) {
      float p0 = fmaxf(Arf[g] * ua.x, Brf[g] * va.x);
      float p1 = fmaxf(Arf[g] * ua.y, Brf[g] * va.y);
      float p2 = fmaxf(Arf[g] * ua.z, Brf[g] * va.z);
      float p3 = fmaxf(Arf[g] * ua.w, Brf[g] * va.w);
      float p4 = fmaxf(Arf[g] * ub.x, Brf[g] * vb.x);
      float p5 = fmaxf(Arf[g] * ub.y, Brf[g] * vb.y);
      float p6 = fmaxf(Arf[g] * ub.z, Brf[g] * vb.z);
      float p7 = fmaxf(Arf[g] * ub.w, Brf[g] * vb.w);
      if (!dense) {
        unsigned byte = (mword[g] >> (q * 8)) & 0xffu;
        p0 = (byte & 1u) ? p0 : 0.f;
        p1 = (byte & 2u) ? p1 : 0.f;
        p2 = (byte & 4u) ? p2 : 0.f;
        p3 = (byte & 8u) ? p3 : 0.f;
        p4 = (byte & 16u) ? p4 : 0.f;
        p5 = (byte & 32u) ? p5 : 0.f;
        p6 = (byte & 64u) ? p6 : 0.f;
        p7 = (byte & 128u) ? p7 : 0.f;
      }
      union { f16x8 v8_; f16x2 v2_[4]; } au;
      au.v2_[0] = __builtin_bit_cast(f16x2, __builtin_amdgcn_cvt_pkrtz(p0, p1));
      au.v2_[1] = __builtin_bit_cast(f16x2, __builtin_amdgcn_cvt_pkrtz(p2, p3));
      au.v2_[2] = __builtin_bit_cast(f16x2, __builtin_amdgcn_cvt_pkrtz(p4, p5));
      au.v2_[3] = __builtin_bit_cast(f16x2, __builtin_amdgcn_cvt_pkrtz(p6, p7));
      acc[g] = __builtin_amdgcn_mfma_f32_16x16x32_f16(au.v8_, bf, acc[g], 0, 0, 0);
      accL[g] = __builtin_amdgcn_mfma_f32_16x16x32_f16(au.v8_, bones, accL[g], 0, 0, 0);
    }
  }

  // epilogue: L[row g*16 + q*4 + rr] sits in lane (q*16), register rr of accL[g]
#pragma unroll
  for (int g = 0; g < 2; ++g) {
#pragma unroll
    for (int rr = 0; rr < 4; ++rr) {
      float Lrow = __shfl(accL[g][rr], q * 16);
      float il = __builtin_amdgcn_rcpf(Lrow);
      out[((size_t)(b * NN + n0 + g * 16 + q * 4 + rr)) * FOUT + head * 64 + wv * 16 + c] =
          acc[g][rr] * il;
    }
  }
}

extern "C" void kernel_launch(void* const* d_in, const int* in_sizes, int n_in,
                              void* d_out, int out_size, void* d_ws, size_t ws_size,
                              hipStream_t stream) {
  const float* x = (const float*)d_in[0];
  const int* adj = (const int*)d_in[1];
  const float* W = (const float*)d_in[2];
  const float* a = (const float*)d_in[3];
  float* out = (float*)d_out;

  char* ws = (char*)d_ws;
  _Float16* hT = (_Float16*)ws;                              // 4 MB
  _Float16* WT = (_Float16*)(ws + (size_t)4 * 1024 * 1024);  // 128 KB
  float* s1_ws = (float*)(ws + (size_t)4 * 1024 * 1024 + 128 * 1024);
  float* u_ws = s1_ws + (size_t)BB * H * NN;
  float* v_ws = u_ws + (size_t)BB * H * NN;
  unsigned* S2maxU = (unsigned*)(v_ws + (size_t)BB * H * NN);  // 32 u32
  unsigned* adjP = S2maxU + 64;                                // 1 MB

  prep<<<1040, 256, 0, stream>>>(adj, adjP, W, WT, S2maxU);
  gemm_xw<<<dim3(128, 4), 256, 0, stream>>>(x, WT, a, hT, s1_ws, u_ws, v_ws, S2maxU);
  attn<<<dim3(32, 32), 256, 0, stream>>>(hT, s1_ws, u_ws, v_ws, S2maxU, adjP, out);
}

// Round 12
// 136.505 us; speedup vs baseline: 2.6584x; 2.6584x over previous
//
#include <hip/hip_runtime.h>
#include <math.h>

#define H 4
#define HD 64
#define NN 1024
#define BB 8
#define FIN 256
#define FOUT 256

typedef _Float16 f16x8 __attribute__((ext_vector_type(8)));
typedef _Float16 f16x4 __attribute__((ext_vector_type(4)));
typedef _Float16 f16x2 __attribute__((ext_vector_type(2)));
typedef float f32x4 __attribute__((ext_vector_type(4)));

__device__ __forceinline__ unsigned fkey(float f) {
  unsigned u = __float_as_uint(f);
  return (u & 0x80000000u) ? ~u : (u | 0x80000000u);
}
__device__ __forceinline__ float fdecode(unsigned k) {
  unsigned u = (k & 0x80000000u) ? (k & 0x7fffffffu) : ~k;
  return __uint_as_float(u);
}

// ---------------------------------------------------------------------------
// Kernel 0: prep. Blocks 0..1023: pack adj -> 1 bit/edge (streaming).
// Blocks 1024..1039: WT[f][k] = (fp16) W[k][f]; block 1024 also zeroes S2maxU.
// ---------------------------------------------------------------------------
__global__ __launch_bounds__(256) void prep(const int* __restrict__ adj,
                                            unsigned* __restrict__ adjP,
                                            const float* __restrict__ W,
                                            _Float16* __restrict__ WT,
                                            unsigned* __restrict__ S2maxU) {
  __shared__ float tile[64][68];
  const int tid = threadIdx.x;
  if (blockIdx.x < 1024) {
    size_t widx = (size_t)blockIdx.x * 256 + tid;  // [0, 8*1024*32)
    const int4* p = (const int4*)adj + widx * 8;
    int4 v[8];
#pragma unroll
    for (int i = 0; i < 8; ++i) v[i] = p[i];
    unsigned bits = 0;
#pragma unroll
    for (int i = 0; i < 8; ++i) {
      bits |= (v[i].x != 0 ? 1u : 0u) << (4 * i);
      bits |= (v[i].y != 0 ? 2u : 0u) << (4 * i);
      bits |= (v[i].z != 0 ? 4u : 0u) << (4 * i);
      bits |= (v[i].w != 0 ? 8u : 0u) << (4 * i);
    }
    adjP[widx] = bits;
  } else {
    if (blockIdx.x == 1024 && tid < 32) S2maxU[tid] = 0u;
    const int bx = blockIdx.x - 1024;
    const int k0 = (bx & 3) * 64, f0 = (bx >> 2) * 64;
    const int r = tid >> 4, c4 = (tid & 15) * 4;
#pragma unroll
    for (int p = 0; p < 4; ++p) {
      float4 v = *(const float4*)&W[(size_t)(k0 + p * 16 + r) * FOUT + f0 + c4];
      *(float4*)&tile[p * 16 + r][c4] = v;
    }
    __syncthreads();
    const int f = tid >> 2, kg = (tid & 3) * 16;
#pragma unroll
    for (int i = 0; i < 4; ++i) {
      f16x4 o;
#pragma unroll
      for (int j = 0; j < 4; ++j) o[j] = (_Float16)tile[kg + i * 4 + j][f];
      *(f16x4*)&WT[(size_t)(f0 + f) * FIN + k0 + kg + i * 4] = o;
    }
  }
}

// ---------------------------------------------------------------------------
// Kernel 1: h = x @ W via fp16 MFMA (validated r7 structure). Epilogue
// stores s1, u=exp(s2), v=exp(0.2*s2) (fp32, unshifted) and per-(b,h)
// atomicMax of s2.
// ---------------------------------------------------------------------------
__global__ __launch_bounds__(256) void gemm_xw(const float* __restrict__ x,
                                               const _Float16* __restrict__ WT,
                                               const float* __restrict__ a,
                                               _Float16* __restrict__ hT,
                                               float* __restrict__ s1_ws,
                                               float* __restrict__ u_ws,
                                               float* __restrict__ v_ws,
                                               unsigned* __restrict__ S2maxU) {
  __shared__ _Float16 wl[64][264];
  const int tid = threadIdx.x;
  const int lane = tid & 63, w = tid >> 6;
  const int c = lane & 15, q = lane >> 4;
  const int bn0 = blockIdx.x * 64;
  const int head = blockIdx.y;
  const int b = bn0 >> 10, nb = bn0 & 1023;
  const int bh = b * H + head;

  {
    const int row = tid >> 2, kseg = (tid & 3) * 64;
    const _Float16* wp = WT + (size_t)(head * 64 + row) * FIN + kseg;
#pragma unroll
    for (int i = 0; i < 8; ++i) {
      f16x8 t = *(const f16x8*)(wp + i * 8);
      *(f16x8*)&wl[row][kseg + i * 8] = t;
    }
  }
  __syncthreads();

  f32x4 acc[4];
#pragma unroll
  for (int t = 0; t < 4; ++t) acc[t] = (f32x4){0.f, 0.f, 0.f, 0.f};
  const float* xp = x + (size_t)(bn0 + w * 16 + c) * FIN + q * 8;
#pragma unroll
  for (int ks = 0; ks < 8; ++ks) {
    float4 xa = *(const float4*)(xp + ks * 32);
    float4 xb = *(const float4*)(xp + ks * 32 + 4);
    f16x8 af;
    af[0] = (_Float16)xa.x; af[1] = (_Float16)xa.y;
    af[2] = (_Float16)xa.z; af[3] = (_Float16)xa.w;
    af[4] = (_Float16)xb.x; af[5] = (_Float16)xb.y;
    af[6] = (_Float16)xb.z; af[7] = (_Float16)xb.w;
#pragma unroll
    for (int t = 0; t < 4; ++t) {
      f16x8 bf = *(const f16x8*)&wl[t * 16 + c][ks * 32 + q * 8];
      acc[t] = __builtin_amdgcn_mfma_f32_16x16x32_f16(af, bf, acc[t], 0, 0, 0);
    }
  }

  float a1v[4], a2v[4];
#pragma unroll
  for (int t = 0; t < 4; ++t) {
    a1v[t] = a[head * 2 * HD + t * 16 + c];
    a2v[t] = a[head * 2 * HD + HD + t * 16 + c];
  }
  float s1p[4] = {0.f, 0.f, 0.f, 0.f};
  float s2p[4] = {0.f, 0.f, 0.f, 0.f};
#pragma unroll
  for (int t = 0; t < 4; ++t) {
    f16x4 hv;
#pragma unroll
    for (int rr = 0; rr < 4; ++rr) {
      hv[rr] = (_Float16)acc[t][rr];
      s1p[rr] += acc[t][rr] * a1v[t];
      s2p[rr] += acc[t][rr] * a2v[t];
    }
    *(f16x4*)&hT[((size_t)(bh * 64 + t * 16 + c)) * NN + nb + w * 16 + q * 4] = hv;
  }
  float ms2 = -INFINITY;
#pragma unroll
  for (int rr = 0; rr < 4; ++rr) {
    float s1 = s1p[rr], s2 = s2p[rr];
#pragma unroll
    for (int off = 8; off; off >>= 1) {
      s1 += __shfl_xor(s1, off);
      s2 += __shfl_xor(s2, off);
    }
    ms2 = fmaxf(ms2, s2);
    if (c == 0) {
      int n = nb + w * 16 + q * 4 + rr;
      size_t idx = (size_t)bh * NN + n;
      s1_ws[idx] = s1;
      u_ws[idx] = __expf(s2);
      v_ws[idx] = __expf(0.2f * s2);
    }
  }
  ms2 = fmaxf(ms2, __shfl_xor(ms2, 16));
  ms2 = fmaxf(ms2, __shfl_xor(ms2, 32));
  if (lane == 0) atomicMax(&S2maxU[bh], fkey(ms2));
}

// ---------------------------------------------------------------------------
// Kernel 2: attention. Block = 32 rows x (b,h): 1024 blocks (4/CU natural).
// No LDS in the hot loop; depth-2 prefetch via EXPLICIT NAMED slot variables
// (A=even, B=odd chunks; kc loop manually unrolled 2x) so nothing is
// dynamically indexed -> no scratch. p = max(Ar*u, Br*v); L via ones-column
// MFMA; rcp epilogue; mask path only when adj not all-ones.
// ---------------------------------------------------------------------------
__global__ __launch_bounds__(256) void attn(const _Float16* __restrict__ hT,
                                            const float* __restrict__ s1_ws,
                                            const float* __restrict__ u_ws,
                                            const float* __restrict__ v_ws,
                                            const unsigned* __restrict__ S2maxU,
                                            const unsigned* __restrict__ adjP,
                                            float* __restrict__ out) {
  __shared__ unsigned adjW[32][36];  // 4.6 KB, padded
  __shared__ int denseFlag;
  const int tid = threadIdx.x, lane = tid & 63, wv = tid >> 6;
  const int c = lane & 15, q = lane >> 4;
  const int ntile = blockIdx.x, bh = blockIdx.y;
  const int b = bh >> 2, head = bh & 3;
  const int n0 = ntile * 32;

  if (tid == 0) denseFlag = 1;
  __syncthreads();
  {
    const int row = tid >> 3, wo = (tid & 7) * 4;  // 32 rows x 32 words
    uint4 m0 = *(const uint4*)(adjP + ((size_t)(b * NN + n0 + row)) * 32 + wo);
    *(uint4*)&adjW[row][wo] = m0;
    if ((m0.x & m0.y & m0.z & m0.w) != 0xffffffffu) atomicAnd(&denseFlag, 0);
  }
  __syncthreads();
  const int dense = denseFlag;

  const float S2 = fdecode(S2maxU[bh]);
  float Arf[2], Brf[2];
#pragma unroll
  for (int g = 0; g < 2; ++g) {
    float s1 = s1_ws[(size_t)bh * NN + n0 + g * 16 + c];
    float t = s1 + S2;
    float M = fmaxf(t, 0.2f * t);
    Arf[g] = __expf(s1 - M);
    Brf[g] = __expf(0.2f * s1 - M);
  }

  f32x4 acc0 = (f32x4){0.f, 0.f, 0.f, 0.f}, acc1 = acc0;
  f32x4 accL0 = acc0, accL1 = acc0;
  f16x8 bones;
  {
    _Float16 o = (c == 0) ? (_Float16)1.0f : (_Float16)0.0f;
#pragma unroll
    for (int j = 0; j < 8; ++j) bones[j] = o;
  }

  const _Float16* bp = hT + ((size_t)bh * 64 + wv * 16 + c) * NN + q * 8;
  const float* up = u_ws + (size_t)bh * NN + q * 8;
  const float* vp = v_ws + (size_t)bh * NN + q * 8;

  // one-chunk worker (all state by value / reference, no arrays)
  auto chunk = [&](f16x8 bf, float4 ua, float4 ub, float4 va, float4 vb, int kc) {
    unsigned mw0 = 0, mw1 = 0;
    if (!dense) {
      mw0 = adjW[c][kc];
      mw1 = adjW[16 + c][kc];
    }
#pragma unroll
    for (int g = 0; g < 2; ++g) {
      const float Ar = Arf[g], Br = Brf[g];
      float p0 = fmaxf(Ar * ua.x, Br * va.x);
      float p1 = fmaxf(Ar * ua.y, Br * va.y);
      float p2 = fmaxf(Ar * ua.z, Br * va.z);
      float p3 = fmaxf(Ar * ua.w, Br * va.w);
      float p4 = fmaxf(Ar * ub.x, Br * vb.x);
      float p5 = fmaxf(Ar * ub.y, Br * vb.y);
      float p6 = fmaxf(Ar * ub.z, Br * vb.z);
      float p7 = fmaxf(Ar * ub.w, Br * vb.w);
      if (!dense) {
        unsigned byte = ((g ? mw1 : mw0) >> (q * 8)) & 0xffu;
        p0 = (byte & 1u) ? p0 : 0.f;
        p1 = (byte & 2u) ? p1 : 0.f;
        p2 = (byte & 4u) ? p2 : 0.f;
        p3 = (byte & 8u) ? p3 : 0.f;
        p4 = (byte & 16u) ? p4 : 0.f;
        p5 = (byte & 32u) ? p5 : 0.f;
        p6 = (byte & 64u) ? p6 : 0.f;
        p7 = (byte & 128u) ? p7 : 0.f;
      }
      union { f16x8 v8_; f16x2 v2_[4]; } au;
      au.v2_[0] = __builtin_bit_cast(f16x2, __builtin_amdgcn_cvt_pkrtz(p0, p1));
      au.v2_[1] = __builtin_bit_cast(f16x2, __builtin_amdgcn_cvt_pkrtz(p2, p3));
      au.v2_[2] = __builtin_bit_cast(f16x2, __builtin_amdgcn_cvt_pkrtz(p4, p5));
      au.v2_[3] = __builtin_bit_cast(f16x2, __builtin_amdgcn_cvt_pkrtz(p6, p7));
      if (g == 0) {
        acc0 = __builtin_amdgcn_mfma_f32_16x16x32_f16(au.v8_, bf, acc0, 0, 0, 0);
        accL0 = __builtin_amdgcn_mfma_f32_16x16x32_f16(au.v8_, bones, accL0, 0, 0, 0);
      } else {
        acc1 = __builtin_amdgcn_mfma_f32_16x16x32_f16(au.v8_, bf, acc1, 0, 0, 0);
        accL1 = __builtin_amdgcn_mfma_f32_16x16x32_f16(au.v8_, bones, accL1, 0, 0, 0);
      }
    }
  };

  // slot A = even chunk, slot B = odd chunk (explicit names, no arrays)
  f16x8 bfA = *(const f16x8*)bp;
  float4 uaA = *(const float4*)up, ubA = *(const float4*)(up + 4);
  float4 vaA = *(const float4*)vp, vbA = *(const float4*)(vp + 4);
  f16x8 bfB = *(const f16x8*)(bp + 32);
  float4 uaB = *(const float4*)(up + 32), ubB = *(const float4*)(up + 36);
  float4 vaB = *(const float4*)(vp + 32), vbB = *(const float4*)(vp + 36);

  for (int kc2 = 0; kc2 < 16; ++kc2) {
    const int kc0 = kc2 * 2, kc1 = kc0 + 1;
    f16x8 bf = bfA;
    float4 ua = uaA, ub = ubA, va = vaA, vb = vbA;
    if (kc2 < 15) {
      bfA = *(const f16x8*)(bp + (kc0 + 2) * 32);
      uaA = *(const float4*)(up + (kc0 + 2) * 32);
      ubA = *(const float4*)(up + (kc0 + 2) * 32 + 4);
      vaA = *(const float4*)(vp + (kc0 + 2) * 32);
      vbA = *(const float4*)(vp + (kc0 + 2) * 32 + 4);
    }
    chunk(bf, ua, ub, va, vb, kc0);
    bf = bfB;
    ua = uaB; ub = ubB; va = vaB; vb = vbB;
    if (kc2 < 15) {
      bfB = *(const f16x8*)(bp + (kc1 + 2) * 32);
      uaB = *(const float4*)(up + (kc1 + 2) * 32);
      ubB = *(const float4*)(up + (kc1 + 2) * 32 + 4);
      vaB = *(const float4*)(vp + (kc1 + 2) * 32);
      vbB = *(const float4*)(vp + (kc1 + 2) * 32 + 4);
    }
    chunk(bf, ua, ub, va, vb, kc1);
  }

  // epilogue: L[row g*16 + q*4 + rr] sits in lane (q*16), register rr of accL[g]
#pragma unroll
  for (int rr = 0; rr < 4; ++rr) {
    float L0 = __shfl(accL0[rr], q * 16);
    float L1 = __shfl(accL1[rr], q * 16);
    float il0 = __builtin_amdgcn_rcpf(L0);
    float il1 = __builtin_amdgcn_rcpf(L1);
    out[((size_t)(b * NN + n0 + q * 4 + rr)) * FOUT + head * 64 + wv * 16 + c] =
        acc0[rr] * il0;
    out[((size_t)(b * NN + n0 + 16 + q * 4 + rr)) * FOUT + head * 64 + wv * 16 + c] =
        acc1[rr] * il1;
  }
}

extern "C" void kernel_launch(void* const* d_in, const int* in_sizes, int n_in,
                              void* d_out, int out_size, void* d_ws, size_t ws_size,
                              hipStream_t stream) {
  const float* x = (const float*)d_in[0];
  const int* adj = (const int*)d_in[1];
  const float* W = (const float*)d_in[2];
  const float* a = (const float*)d_in[3];
  float* out = (float*)d_out;

  char* ws = (char*)d_ws;
  _Float16* hT = (_Float16*)ws;                              // 4 MB
  _Float16* WT = (_Float16*)(ws + (size_t)4 * 1024 * 1024);  // 128 KB
  float* s1_ws = (float*)(ws + (size_t)4 * 1024 * 1024 + 128 * 1024);
  float* u_ws = s1_ws + (size_t)BB * H * NN;
  float* v_ws = u_ws + (size_t)BB * H * NN;
  unsigned* S2maxU = (unsigned*)(v_ws + (size_t)BB * H * NN);  // 32 u32
  unsigned* adjP = S2maxU + 64;                                // 1 MB

  prep<<<1040, 256, 0, stream>>>(adj, adjP, W, WT, S2maxU);
  gemm_xw<<<dim3(128, 4), 256, 0, stream>>>(x, WT, a, hT, s1_ws, u_ws, v_ws, S2maxU);
  attn<<<dim3(32, 32), 256, 0, stream>>>(hT, s1_ws, u_ws, v_ws, S2maxU, adjP, out);
}